// Round 2
// baseline (897.644 us; speedup 1.0000x reference)
//
#include <hip/hip_runtime.h>

typedef __bf16 bf16;
typedef bf16 bf16x4 __attribute__((ext_vector_type(4)));
typedef bf16 bf16x8 __attribute__((ext_vector_type(8)));
typedef float f32x4 __attribute__((ext_vector_type(4)));

#define LOG2E 1.4426950408889634f

__device__ __forceinline__ f32x4 mfma16(bf16x8 a, bf16x8 b, f32x4 c) {
    return __builtin_amdgcn_mfma_f32_16x16x32_bf16(a, b, c, 0, 0, 0);
}

// async global->LDS, 16B per lane. LDS dest is wave-uniform base + lane*16.
__device__ __forceinline__ void async16(const void* g, void* l) {
    __builtin_amdgcn_global_load_lds(
        (const __attribute__((address_space(1))) void*)g,
        (__attribute__((address_space(3))) void*)l, 16, 0, 0);
}

// ---------------------------------------------------------------------------
// prep_w: W{1,2}t[n][k] = (sum_c W_reduce[k][c] * W_qkv[c][n]) * colscale(n)
// colscale folds w_ds*rs (branch1 q) / w_uds*rs (branch2 q) / w_uds (branch2 k);
// bias[z][n] folds b_uds (*rs for q part). rs = d^-0.5 folded into q side.
// grid (8 k-blocks of 64, 48 n-blocks of 16, 2 branches), 256 thr.
// ---------------------------------------------------------------------------
__global__ __launch_bounds__(256) void prep_w(
    const float* __restrict__ Wr, const float* __restrict__ Wq,
    const float* __restrict__ w_ds, const float* __restrict__ w_uds,
    const float* __restrict__ b_uds,
    bf16* __restrict__ W1t, bf16* __restrict__ W2t, float* __restrict__ bias) {
    __shared__ float wq[256][17];
    const int t = threadIdx.x;
    const int k0 = blockIdx.x * 64, n0 = blockIdx.y * 16, z = blockIdx.z;
#pragma unroll
    for (int i = 0; i < 16; i++) {
        int c = i * 16 + (t >> 4);
        wq[c][t & 15] = Wq[c * 768 + n0 + (t & 15)];
    }
    __syncthreads();
    const int j = t & 15, n = n0 + j;
    const float rs = 0.17677669529663687f;  // 1/sqrt(32)
    float scale, bv;
    if (z == 0) {
        scale = (n < 256) ? w_ds[n] * rs : 1.f; bv = 0.f;
    } else if (n < 256) {
        scale = w_uds[n] * rs; bv = b_uds[n] * rs;
    } else if (n < 512) {
        scale = w_uds[n - 256]; bv = b_uds[n - 256];
    } else {
        scale = 1.f; bv = 0.f;
    }
    bf16* Wt = z ? W2t : W1t;
#pragma unroll 1
    for (int i = 0; i < 4; i++) {
        int k = k0 + (t >> 4) * 4 + i;
        float acc = 0.f;
        for (int c = 0; c < 256; c++) acc = fmaf(Wr[k * 256 + c], wq[c][j], acc);
        Wt[n * 512 + k] = (bf16)(acc * scale);
    }
    if (blockIdx.x == 0 && (t >> 4) == 0) bias[z * 768 + n] = bv;
}

// Wpt[n][k] = W_proj[k][n], bf16.  grid 512 blocks x 256 thr.
__global__ void prep_wp(const float* __restrict__ Wp, bf16* __restrict__ Wpt) {
    const int n = blockIdx.x, k = threadIdx.x;
    Wpt[n * 256 + k] = (bf16)Wp[k * 512 + n];
}

// ---------------------------------------------------------------------------
// gemm_qkv: Out[m][n] = sum_k X[m][k]*Wt[n][k] + bias[n];  M=73984 K=512 N=768
// A fp32 (converted to bf16 during staging), B bf16 via global_load_lds.
// grid (6 n-blocks, 578 m-blocks) - n fastest for A-tile L2 reuse.
// ---------------------------------------------------------------------------
__global__ __launch_bounds__(256) void gemm_qkv(
    const float* __restrict__ X, const bf16* __restrict__ Wt,
    const float* __restrict__ biasp, bf16* __restrict__ Out) {
    // A stride 48 (16B-aligned rows, breaks the worst bank aliasing)
    __shared__ __attribute__((aligned(16))) bf16 As[128 * 48];
    __shared__ __attribute__((aligned(16))) bf16 Bs[128 * 32];
    const int tid = threadIdx.x;
    const int lane = tid & 63, wave = tid >> 6;
    const int ln = lane & 15, quad = lane >> 4;
    const int bn = blockIdx.x * 128, bm = blockIdx.y * 128;
    const int wm = (wave & 1) * 64, wn = (wave >> 1) * 64;
    f32x4 acc[4][4] = {};
    float bi[4];
#pragma unroll
    for (int nt = 0; nt < 4; nt++) bi[nt] = biasp[bn + wn + nt * 16 + ln];
    const int brow = bn + wave * 32 + (lane >> 2);
    const int bcol0 = (lane & 3) * 8;
    bf16* bs_base0 = &Bs[(wave * 32) * 32];
    bf16* bs_base1 = &Bs[(wave * 32 + 16) * 32];

    for (int kb = 0; kb < 512; kb += 32) {
#pragma unroll
        for (int i = 0; i < 4; i++) {
            int idx = tid + i * 256;
            int row = idx >> 3;
            int c4 = (idx & 7) * 4;
            float4 v = *(const float4*)&X[(bm + row) * 512 + kb + c4];
            bf16x4 w = {(bf16)v.x, (bf16)v.y, (bf16)v.z, (bf16)v.w};
            *(bf16x4*)&As[row * 48 + c4] = w;
        }
        async16(&Wt[brow * 512 + kb + bcol0], bs_base0);
        async16(&Wt[(brow + 16) * 512 + kb + bcol0], bs_base1);
        __syncthreads();
        bf16x8 a[4], b[4];
#pragma unroll
        for (int mt = 0; mt < 4; mt++)
            a[mt] = *(const bf16x8*)&As[(wm + mt * 16 + ln) * 48 + quad * 8];
#pragma unroll
        for (int nt = 0; nt < 4; nt++)
            b[nt] = *(const bf16x8*)&Bs[(wn + nt * 16 + ln) * 32 + quad * 8];
#pragma unroll
        for (int mt = 0; mt < 4; mt++)
#pragma unroll
            for (int nt = 0; nt < 4; nt++)
                acc[mt][nt] = mfma16(a[mt], b[nt], acc[mt][nt]);
        __syncthreads();
    }
#pragma unroll
    for (int mt = 0; mt < 4; mt++)
#pragma unroll
        for (int nt = 0; nt < 4; nt++) {
            int col = bn + wn + nt * 16 + ln;
#pragma unroll
            for (int r = 0; r < 4; r++) {
                int row = bm + wm + mt * 16 + quad * 4 + r;
                Out[row * 768 + col] = (bf16)(acc[mt][nt][r] + bi[nt]);
            }
        }
}

// ---------------------------------------------------------------------------
// gemm_proj: Y[m][n] = sum_k A[m][k]*Wt[n][k] + bp[n];  M=73984 K=256 N=512
// A,B both bf16 via global_load_lds.  grid (4 n-blocks, 578 m-blocks).
// ---------------------------------------------------------------------------
__global__ __launch_bounds__(256) void gemm_proj(
    const bf16* __restrict__ A, const bf16* __restrict__ Wt,
    const float* __restrict__ bp, float* __restrict__ Y) {
    __shared__ __attribute__((aligned(16))) bf16 As[128 * 32];
    __shared__ __attribute__((aligned(16))) bf16 Bs[128 * 32];
    const int tid = threadIdx.x;
    const int lane = tid & 63, wave = tid >> 6;
    const int ln = lane & 15, quad = lane >> 4;
    const int bn = blockIdx.x * 128, bm = blockIdx.y * 128;
    const int wm = (wave & 1) * 64, wn = (wave >> 1) * 64;
    f32x4 acc[4][4] = {};
    float bi[4];
#pragma unroll
    for (int nt = 0; nt < 4; nt++) bi[nt] = bp[bn + wn + nt * 16 + ln];
    const int arow = bm + wave * 32 + (lane >> 2);
    const int brow = bn + wave * 32 + (lane >> 2);
    const int c0 = (lane & 3) * 8;
    bf16* as0 = &As[(wave * 32) * 32];
    bf16* as1 = &As[(wave * 32 + 16) * 32];
    bf16* bs0 = &Bs[(wave * 32) * 32];
    bf16* bs1 = &Bs[(wave * 32 + 16) * 32];

    for (int kb = 0; kb < 256; kb += 32) {
        async16(&A[arow * 256 + kb + c0], as0);
        async16(&A[(arow + 16) * 256 + kb + c0], as1);
        async16(&Wt[brow * 256 + kb + c0], bs0);
        async16(&Wt[(brow + 16) * 256 + kb + c0], bs1);
        __syncthreads();
        bf16x8 a[4], b[4];
#pragma unroll
        for (int mt = 0; mt < 4; mt++)
            a[mt] = *(const bf16x8*)&As[(wm + mt * 16 + ln) * 32 + quad * 8];
#pragma unroll
        for (int nt = 0; nt < 4; nt++)
            b[nt] = *(const bf16x8*)&Bs[(wn + nt * 16 + ln) * 32 + quad * 8];
#pragma unroll
        for (int mt = 0; mt < 4; mt++)
#pragma unroll
            for (int nt = 0; nt < 4; nt++)
                acc[mt][nt] = mfma16(a[mt], b[nt], acc[mt][nt]);
        __syncthreads();
    }
#pragma unroll
    for (int mt = 0; mt < 4; mt++)
#pragma unroll
        for (int nt = 0; nt < 4; nt++) {
            int col = bn + wn + nt * 16 + ln;
#pragma unroll
            for (int r = 0; r < 4; r++) {
                int row = bm + wm + mt * 16 + quad * 4 + r;
                Y[row * 512 + col] = acc[mt][nt][r] + bi[nt];
            }
        }
}

// ---------------------------------------------------------------------------
// attn: per (chunk, batch) block, 4 waves, each wave does heads {w, w+4}.
// QKV row layout: [q(256) | k(256) | v(256)], all scales/bias pre-folded.
// S = Q·K^T (scale folded), softmax over keys, O = P·V, write o[b,n,h*32+d].
// All LDS is wave-private -> no barriers.
// ---------------------------------------------------------------------------
__global__ __launch_bounds__(256) void attn(const bf16* __restrict__ QKV,
                                            bf16* __restrict__ O) {
    __shared__ __attribute__((aligned(16))) bf16 vT[4][32 * 104];
    __shared__ __attribute__((aligned(16))) bf16 P[4][16 * 104];
    const int tid = threadIdx.x;
    const int lane = tid & 63, wave = tid >> 6;
    const int ln = lane & 15, quad = lane >> 4;
    const int chunk = blockIdx.x, b = blockIdx.y;
    const int s = chunk * 73;
    const int mc = min(289 - s, 73);  // chunk length (73,73,73,70)
    const int rowbase = b * 289 + s;
    bf16* vTw = &vT[wave][0];
    bf16* Pw = &P[wave][0];
    const f32x4 zero4 = {0.f, 0.f, 0.f, 0.f};

    // zero P pad cols [80,96) once (read by PV m-chunk 2, never written otherwise)
    {
        bf16x4 z = {(bf16)0.f, (bf16)0.f, (bf16)0.f, (bf16)0.f};
        *(bf16x4*)&Pw[(lane >> 2) * 104 + 80 + (lane & 3) * 4] = z;
    }

#pragma unroll 1
    for (int hi = 0; hi < 2; hi++) {
        const int h = wave + hi * 4;
        const int cq = h * 32, ck = 256 + h * 32, cv = 512 + h * 32;

        // stage V transposed: vT[d][m].  NOTE: cover m=0..95 (clamped) so the
        // vf[*][2] fragment (m 64..95) never reads uninitialized LDS — the
        // matching P cols [80,96) are zero, but 0*NaN-garbage = NaN (round-1 bug).
#pragma unroll
        for (int p5 = 0; p5 < 6; p5++) {
            int m = p5 * 16 + (lane >> 2);
            int mr = min(m, mc - 1);
            bf16x8 v8 = *(const bf16x8*)&QKV[(rowbase + mr) * 768 + cv + (lane & 3) * 8];
            int d0 = (lane & 3) * 8;
#pragma unroll
            for (int j = 0; j < 8; j++) vTw[(d0 + j) * 104 + m] = v8[j];
        }
        // K fragments (B-operand pattern: lane&15 -> key row, quad*8 -> d)
        bf16x8 kf[5];
#pragma unroll
        for (int mt = 0; mt < 5; mt++) {
            int mr = min(mt * 16 + ln, mc - 1);
            kf[mt] = *(const bf16x8*)&QKV[(rowbase + mr) * 768 + ck + quad * 8];
        }
        // V fragments (B-operand: lane&15 -> d row of vT, quad*8 -> m)
        bf16x8 vf[2][3];
#pragma unroll
        for (int dt = 0; dt < 2; dt++)
#pragma unroll
            for (int mk = 0; mk < 3; mk++)
                vf[dt][mk] = *(const bf16x8*)&vTw[(dt * 16 + ln) * 104 + mk * 32 + quad * 8];

#pragma unroll 1
        for (int nt = 0; nt < 5; nt++) {
            int qr = min(nt * 16 + ln, mc - 1);
            bf16x8 qf = *(const bf16x8*)&QKV[(rowbase + qr) * 768 + cq + quad * 8];
            f32x4 S[5];
#pragma unroll
            for (int mt = 0; mt < 5; mt++) S[mt] = mfma16(qf, kf[mt], zero4);
            // mask padded key columns (C layout: col = lane&15)
#pragma unroll
            for (int mt = 0; mt < 5; mt++)
                if (mt * 16 + ln >= mc) {
                    S[mt][0] = -1e30f; S[mt][1] = -1e30f;
                    S[mt][2] = -1e30f; S[mt][3] = -1e30f;
                }
            // row softmax: rows = quad*4+r, reduce over 16 col-lanes + 5 tiles
            float mxv[4], sm[4];
#pragma unroll
            for (int r = 0; r < 4; r++) {
                float m0 = S[0][r];
#pragma unroll
                for (int mt = 1; mt < 5; mt++) m0 = fmaxf(m0, S[mt][r]);
                m0 = fmaxf(m0, __shfl_xor(m0, 1));
                m0 = fmaxf(m0, __shfl_xor(m0, 2));
                m0 = fmaxf(m0, __shfl_xor(m0, 4));
                m0 = fmaxf(m0, __shfl_xor(m0, 8));
                mxv[r] = m0;
                sm[r] = 0.f;
            }
#pragma unroll
            for (int mt = 0; mt < 5; mt++)
#pragma unroll
                for (int r = 0; r < 4; r++) {
                    float p = exp2f((S[mt][r] - mxv[r]) * LOG2E);
                    sm[r] += p;
                    Pw[(quad * 4 + r) * 104 + mt * 16 + ln] = (bf16)p;
                }
#pragma unroll
            for (int r = 0; r < 4; r++) {
                float t = sm[r];
                t += __shfl_xor(t, 1);
                t += __shfl_xor(t, 2);
                t += __shfl_xor(t, 4);
                t += __shfl_xor(t, 8);
                sm[r] = 1.0f / t;
            }
            // PV: A = P rows (lane&15 -> n, quad*8 -> m), B = vf
            f32x4 o0 = zero4, o1 = zero4;
#pragma unroll
            for (int mk = 0; mk < 3; mk++) {
                bf16x8 pa = *(const bf16x8*)&Pw[ln * 104 + mk * 32 + quad * 8];
                o0 = mfma16(pa, vf[0][mk], o0);
                o1 = mfma16(pa, vf[1][mk], o1);
            }
#pragma unroll
            for (int r = 0; r < 4; r++) {
                int nl = nt * 16 + quad * 4 + r;
                if (nl < mc) {
                    int orow = (rowbase + nl) * 256 + h * 32;
                    O[orow + ln] = (bf16)(o0[r] * sm[r]);
                    O[orow + 16 + ln] = (bf16)(o1[r] * sm[r]);
                }
            }
        }
    }
}

// ---------------------------------------------------------------------------
extern "C" void kernel_launch(void* const* d_in, const int* in_sizes, int n_in,
                              void* d_out, int out_size, void* d_ws, size_t ws_size,
                              hipStream_t stream) {
    (void)in_sizes; (void)n_in; (void)out_size;
    const float* x1 = (const float*)d_in[0];
    const float* x2 = (const float*)d_in[1];
    const float* Wr = (const float*)d_in[2];
    const float* Wq = (const float*)d_in[3];
    const float* Wp = (const float*)d_in[4];
    const float* bp = (const float*)d_in[5];
    const float* w_ds = (const float*)d_in[6];
    const float* w_uds = (const float*)d_in[7];
    const float* b_uds = (const float*)d_in[8];

    char* ws = (char*)d_ws;
    bf16* W1t = (bf16*)(ws);                     //  786432 B
    bf16* W2t = (bf16*)(ws + 786432);            //  786432 B
    bf16* Wpt = (bf16*)(ws + 1572864);           //  262144 B
    float* bias = (float*)(ws + 1835008);        //    6144 B
    bf16* ob = (bf16*)(ws + 1841152);            // 37879808 B  (o buffer)
    float* out = (float*)d_out;
    // qkv scratch: prefer d_ws when it's big enough (deterministic choice per
    // session -> graph-capture safe); else use the not-yet-written second half
    // of d_out (fully consumed by attn before gemm_proj(br1) overwrites it).
    bf16* qkv;
    if (ws_size >= (size_t)39720960 + 113639424) {
        qkv = (bf16*)(ws + 39720960);
    } else {
        qkv = (bf16*)(out + 37879808);           // 113639424 B
    }

    prep_w<<<dim3(8, 48, 2), 256, 0, stream>>>(Wr, Wq, w_ds, w_uds, b_uds, W1t, W2t, bias);
    prep_wp<<<dim3(512), 256, 0, stream>>>(Wp, Wpt);
    for (int br = 0; br < 2; br++) {
        const float* X = br ? x2 : x1;
        const bf16* Wt = br ? W2t : W1t;
        gemm_qkv<<<dim3(6, 578), 256, 0, stream>>>(X, Wt, bias + br * 768, qkv);
        attn<<<dim3(4, 256), 256, 0, stream>>>(qkv, ob);
        gemm_proj<<<dim3(4, 578), 256, 0, stream>>>(ob, Wpt, bp, out + (size_t)br * 37879808);
    }
}